// Round 4
// baseline (353.748 us; speedup 1.0000x reference)
//
#include <hip/hip_runtime.h>
#include <hip/hip_bf16.h>

typedef short bf16x8 __attribute__((ext_vector_type(8)));
typedef short bf16x4 __attribute__((ext_vector_type(4)));
typedef float f32x4  __attribute__((ext_vector_type(4)));

static constexpr int Bb   = 128;
static constexpr int Cin  = 32;
static constexpr int Nn   = 325;
static constexpr int Tt   = 24;
static constexpr int Cout = 64;
static constexpr int VP   = 360;   // padded v length of xT rows (720 B)
static constexpr int SVP  = 352;   // K extent GEMM1 (11 * 32)
static constexpr int WP   = 336;   // padded w rows in stp
static constexpr int NWT  = 21;
static constexpr int NKS  = 11;
static constexpr int TH   = 12;    // t per block
static constexpr size_t XT_ELEMS  = (size_t)Bb * Tt * Cin * VP;
static constexpr size_t STP_ELEMS = (size_t)4 * WP * SVP;

__device__ __forceinline__ void gld16(const void* g, void* l) {
    __builtin_amdgcn_global_load_lds(
        (const __attribute__((address_space(1))) void*)g,
        (__attribute__((address_space(3))) void*)l, 16, 0, 0);
}
__device__ __forceinline__ short bfb(float f) {
    __hip_bfloat16 h = __float2bfloat16(f);
    return *reinterpret_cast<short*>(&h);
}

// ---------------- P1: build S' bf16, w-major, identity-augmented ----------
__global__ void build_stp(const float* __restrict__ sup,
                          __hip_bfloat16* __restrict__ stp) {
    int idx = blockIdx.x * 256 + threadIdx.x;
    int total = 4 * WP * SVP;
    if (idx >= total) return;
    int e = idx / (WP * SVP);
    int r = idx % (WP * SVP);
    int w = r / SVP;
    int v = r % SVP;
    float val = 0.f;
    if (e == 0) {
        val = (v == w && v < Nn) ? 1.f : 0.f;
    } else if (v < Nn && w < Nn) {
        val = sup[((size_t)(e - 1) * Nn + v) * Nn + w];
    }
    stp[idx] = __float2bfloat16(val);
}

// ---------------- P2: x[b][c][v][t] -> xT[(b*T+t)][c][v] bf16 -------------
__global__ void transpose_x(const float* __restrict__ x,
                            __hip_bfloat16* __restrict__ xT) {
    __shared__ float ls[64 * 25];
    int id = blockIdx.x;
    int vt = id % 6;
    int c  = (id / 6) % Cin;
    int b  = id / (6 * Cin);
    int v0 = vt * 64;
    const float* src = x + (size_t)(b * Cin + c) * Nn * Tt;
    for (int i = threadIdx.x; i < 64 * Tt; i += 256) {
        int vi = i / Tt, t = i % Tt;
        int v = v0 + vi;
        ls[vi * 25 + t] = (v < Nn) ? src[(size_t)v * Tt + t] : 0.f;
    }
    __syncthreads();
    for (int j = threadIdx.x; j < 64 * Tt; j += 256) {
        int t = j / 64, vi = j % 64;
        int v = v0 + vi;
        if (v < VP) {
            xT[((size_t)(b * Tt + t) * Cin + c) * VP + v] =
                __float2bfloat16(ls[vi * 25 + t]);
        }
    }
}

// ---------------- M: LDS-staged GEMM1 (Y^T) + register GEMM2 (K=16) -------
__global__ __launch_bounds__(256, 2) void graphconv_main(
    const __hip_bfloat16* __restrict__ xT,
    const __hip_bfloat16* __restrict__ stp,
    const float* __restrict__ W,
    const float* __restrict__ bias,
    float* __restrict__ out) {
    __shared__ alignas(16) __hip_bfloat16 Xs[2][384 * 32];   // 2 x 24576 B
    __shared__ alignas(16) __hip_bfloat16 Ss[2][64 * 32];    // 2 x 4096 B
    __shared__ alignas(16) __hip_bfloat16 Ws[64 * 128];      // 16384 B (swizzled)
    __shared__ float bias_s[Cout];

    // bijective XCD swizzle: 5376 = 8 * 672; consecutive lg share b
    int bid = blockIdx.x;
    int lg  = (bid & 7) * 672 + (bid >> 3);
    int b   = lg / 42;
    int r2  = lg % 42;
    int wt  = r2 >> 1, th = r2 & 1;
    int w0  = wt * 16, t0 = th * TH;

    int tid = threadIdx.x, wid = tid >> 6, lane = tid & 63;
    int cl = lane & 15, kg = lane >> 4;

    // staging lane constants (pre-swizzled SOURCE, linear LDS dest)
    int srow   = lane >> 2;                              // row within 16-row chunk
    int sslotB = (((lane & 3) ^ ((lane >> 3) & 3)) << 4); // swizzled 16B slot
    // read-side swizzle (matches stage): phys slot = kg ^ ((row>>1)&3), row%16==cl
    int xsw = ((kg ^ ((cl >> 1) & 3)) << 4);

    const char* xb = (const char*)(xT + (size_t)(b * Tt + t0) * Cin * VP);
    const char* sb = (const char*)stp;

    // ---- prologue: stage W (fp32->bf16, XOR-swizzled 8B slots) + bias ----
    for (int c2 = tid; c2 < 2048; c2 += 256) {
        int row = c2 >> 5, s = c2 & 31;
        const float* wp = W + (size_t)c2 * 4;
        bf16x4 pk = { bfb(wp[0]), bfb(wp[1]), bfb(wp[2]), bfb(wp[3]) };
        *(bf16x4*)((char*)Ws + row * 256 + ((s ^ (row & 15)) << 3)) = pk;
    }
    if (tid < Cout) bias_s[tid] = bias[tid];

    // ---- stage K-step 0 into buf 0 ----
#pragma unroll
    for (int ii = 0; ii < 6; ++ii) {
        int chunk = wid * 6 + ii;
        gld16(xb + (size_t)(chunk * 16 + srow) * (VP * 2) + sslotB,
              (char*)&Xs[0][0] + chunk * 1024 + lane * 16);
    }
    gld16(sb + ((size_t)(wid * WP + w0 + srow) * SVP) * 2 + sslotB,
          (char*)&Ss[0][0] + wid * 1024 + lane * 16);
    __syncthreads();

    // ---- GEMM1 main loop: Y^T[ct][w], double-buffered LDS ----
    f32x4 acc1[4][6] = {};
    int bb = 0;
    for (int ks = 0; ks < NKS; ++ks) {
        if (ks + 1 < NKS) {   // stage next K-step first (overlaps with compute)
#pragma unroll
            for (int ii = 0; ii < 6; ++ii) {
                int chunk = wid * 6 + ii;
                gld16(xb + (size_t)(chunk * 16 + srow) * (VP * 2) + (ks + 1) * 64 + sslotB,
                      (char*)&Xs[bb ^ 1][0] + chunk * 1024 + lane * 16);
            }
            gld16(sb + ((size_t)(wid * WP + w0 + srow) * SVP) * 2 + (ks + 1) * 64 + sslotB,
                  (char*)&Ss[bb ^ 1][0] + wid * 1024 + lane * 16);
        }
        bf16x8 xf[6], af[4];
#pragma unroll
        for (int j = 0; j < 6; ++j)
            xf[j] = *(const bf16x8*)((const char*)&Xs[bb][0] +
                                     (((wid * 6 + j) * 16 + cl) << 6) + xsw);
#pragma unroll
        for (int e = 0; e < 4; ++e)
            af[e] = *(const bf16x8*)((const char*)&Ss[bb][0] +
                                     (((e * 16 + cl) << 6)) + xsw);
#pragma unroll
        for (int e = 0; e < 4; ++e)
#pragma unroll
            for (int j = 0; j < 6; ++j)
                acc1[e][j] = __builtin_amdgcn_mfma_f32_16x16x32_bf16(
                    xf[j], af[e], acc1[e][j], 0, 0, 0);
        __syncthreads();   // drains vmcnt (stage arrived) + lgkm (reads done)
        bb ^= 1;
    }

    // ---- GEMM2 from registers: out[o][w] += W[o][k16] * Y^T-packets ------
    // lane holds, per (e, j): Y^T rows ct=(wid*6+j)*16+kg*4+r, col w=w0+cl.
    // That is exactly a 16x16x16 B-frag (k = kg*4 + i) for K-window
    // kappa = e*2 + (j&1), N-col = w, t-tile tj = j>>1.
    f32x4 acc2[4][3] = {};
#pragma unroll
    for (int kappa = 0; kappa < 8; ++kappa) {
        int e = kappa >> 1, half = kappa & 1;
        bf16x4 wf[4];
#pragma unroll
        for (int mt = 0; mt < 4; ++mt)
            wf[mt] = *(const bf16x4*)((const char*)Ws + (mt * 16 + cl) * 256 +
                                      ((((kappa * 4 + kg) ^ cl)) << 3));
#pragma unroll
        for (int tj = 0; tj < 3; ++tj) {
            int j = tj * 2 + half;
            f32x4 y = acc1[e][j];
            bf16x4 pb = { bfb(y[0]), bfb(y[1]), bfb(y[2]), bfb(y[3]) };
#pragma unroll
            for (int mt = 0; mt < 4; ++mt)
                acc2[mt][tj] = __builtin_amdgcn_mfma_f32_16x16x16bf16_1k(
                    wf[mt], pb, acc2[mt][tj], 0, 0, 0);
        }
    }

    // ---- epilogue: C/D col=cl -> w, row=kg*4+r -> o; t = t0+wid*3+tj -----
    int w = w0 + cl;
    if (w < Nn) {
#pragma unroll
        for (int mt = 0; mt < 4; ++mt) {
#pragma unroll
            for (int r = 0; r < 4; ++r) {
                int o = mt * 16 + kg * 4 + r;
                size_t base = ((size_t)(b * Cout + o) * Nn + w) * Tt + t0 + wid * 3;
                float bv = bias_s[o];
#pragma unroll
                for (int tj = 0; tj < 3; ++tj)
                    out[base + tj] = acc2[mt][tj][r] + bv;
            }
        }
    }
}

extern "C" void kernel_launch(void* const* d_in, const int* in_sizes, int n_in,
                              void* d_out, int out_size, void* d_ws, size_t ws_size,
                              hipStream_t stream) {
    const float* x    = (const float*)d_in[0];
    const float* sup  = (const float*)d_in[1];
    const float* W    = (const float*)d_in[2];
    const float* bias = (const float*)d_in[3];
    float* out = (float*)d_out;

    __hip_bfloat16* xT  = (__hip_bfloat16*)d_ws;
    __hip_bfloat16* stp = xT + XT_ELEMS;

    build_stp<<<(int)((STP_ELEMS + 255) / 256), 256, 0, stream>>>(sup, stp);
    transpose_x<<<Bb * Cin * 6, 256, 0, stream>>>(x, xT);
    graphconv_main<<<Bb * NWT * 2, 256, 0, stream>>>(xT, stp, W, bias, out);
}